// Round 1
// baseline (172.373 us; speedup 1.0000x reference)
//
#include <hip/hip_runtime.h>

// MAETrimLoss: per-batch sum of k smallest |pred-target|, /(2m), mean over batches.
// Single-pass bit-pattern histogram selection (no sort).

#define NBINS   4096        // top 12 bits of fabsf bit pattern (sign always 0)
#define SHIFT   19          // 32 - 12
#define BATCHES 32
#define M_ELEMS 307200      // 1*480*640
#define K_RANK  245760      // int(0.8 * M_ELEMS)
#define BPB     8           // blocks per batch
#define THREADS 256

__global__ __launch_bounds__(THREADS) void hist_kernel(
    const float* __restrict__ pred, const float* __restrict__ targ,
    unsigned int* __restrict__ gcnt, float* __restrict__ gsum)
{
    __shared__ unsigned int lcnt[NBINS];
    __shared__ float        lsum[NBINS];
    for (int i = threadIdx.x; i < NBINS; i += THREADS) { lcnt[i] = 0u; lsum[i] = 0.0f; }
    __syncthreads();

    const int b   = blockIdx.x / BPB;
    const int seg = blockIdx.x % BPB;
    const int q4_per_batch = M_ELEMS / 4;          // 76800
    const int q4_per_seg   = q4_per_batch / BPB;   // 9600
    const float4* p4 = reinterpret_cast<const float4*>(pred) + (size_t)b * q4_per_batch;
    const float4* t4 = reinterpret_cast<const float4*>(targ) + (size_t)b * q4_per_batch;

    const int i_end = (seg + 1) * q4_per_seg;
    for (int i = seg * q4_per_seg + threadIdx.x; i < i_end; i += THREADS) {
        float4 pv = p4[i];
        float4 tv = t4[i];
        float a; unsigned int bin;
        a = fabsf(pv.x - tv.x); bin = __float_as_uint(a) >> SHIFT;
        atomicAdd(&lcnt[bin], 1u); atomicAdd(&lsum[bin], a);
        a = fabsf(pv.y - tv.y); bin = __float_as_uint(a) >> SHIFT;
        atomicAdd(&lcnt[bin], 1u); atomicAdd(&lsum[bin], a);
        a = fabsf(pv.z - tv.z); bin = __float_as_uint(a) >> SHIFT;
        atomicAdd(&lcnt[bin], 1u); atomicAdd(&lsum[bin], a);
        a = fabsf(pv.w - tv.w); bin = __float_as_uint(a) >> SHIFT;
        atomicAdd(&lcnt[bin], 1u); atomicAdd(&lsum[bin], a);
    }
    __syncthreads();

    unsigned int* bc = gcnt + (size_t)b * NBINS;
    float*        bs = gsum + (size_t)b * NBINS;
    for (int i = threadIdx.x; i < NBINS; i += THREADS) {
        unsigned int c = lcnt[i];
        if (c) {
            atomicAdd(&bc[i], c);
            atomicAdd(&bs[i], lsum[i]);
        }
    }
}

__global__ __launch_bounds__(256) void select_kernel(
    const unsigned int* __restrict__ gcnt, const float* __restrict__ gsum,
    float* __restrict__ out)
{
    const int b = blockIdx.x;
    const unsigned int* cnt = gcnt + (size_t)b * NBINS;
    const float*        sum = gsum + (size_t)b * NBINS;

    __shared__ unsigned int ccnt[256];
    __shared__ float        csum[256];

    const int per = NBINS / 256;  // 16
    const int t0  = threadIdx.x * per;
    unsigned int c = 0; float s = 0.0f;
    for (int i = 0; i < per; ++i) { c += cnt[t0 + i]; s += sum[t0 + i]; }
    ccnt[threadIdx.x] = c; csum[threadIdx.x] = s;
    __syncthreads();

    if (threadIdx.x == 0) {
        // coarse scan over 256 chunk totals
        unsigned int cum = 0; float vacc = 0.0f; int chunk = 255;
        for (int i = 0; i < 256; ++i) {
            if (cum + ccnt[i] >= (unsigned int)K_RANK) { chunk = i; break; }
            cum += ccnt[i]; vacc += csum[i];
        }
        // fine scan within the chunk
        float S = vacc;
        unsigned int cum2 = cum;
        for (int i = chunk * per; i < chunk * per + per; ++i) {
            unsigned int cb = cnt[i];
            if (cum2 + cb >= (unsigned int)K_RANK) {
                unsigned int r = (unsigned int)K_RANK - cum2;  // 1..cb
                float lo = __uint_as_float(((unsigned int)i) << SHIFT);
                float hi = __uint_as_float(((unsigned int)(i + 1)) << SHIFT);
                // rank-interpolated threshold + trapezoid partial sum
                float T = lo + (hi - lo) * ((float)r / (float)cb);
                S += 0.5f * (lo + T) * (float)r;
                break;
            }
            cum2 += cb; S += sum[i];
        }
        atomicAdd(out, S * (1.0f / (2.0f * (float)M_ELEMS * (float)BATCHES)));
    }
}

extern "C" void kernel_launch(void* const* d_in, const int* in_sizes, int n_in,
                              void* d_out, int out_size, void* d_ws, size_t ws_size,
                              hipStream_t stream)
{
    const float* pred = (const float*)d_in[0];
    const float* targ = (const float*)d_in[1];
    // d_in[2] (mask) is unused by the reference.
    float* out = (float*)d_out;

    unsigned int* gcnt = (unsigned int*)d_ws;
    float*        gsum = (float*)((char*)d_ws + (size_t)BATCHES * NBINS * sizeof(unsigned int));

    // zero histograms (ws is poisoned 0xAA before every call) and the output accumulator
    hipMemsetAsync(d_ws, 0, (size_t)BATCHES * NBINS * (sizeof(unsigned int) + sizeof(float)), stream);
    hipMemsetAsync(d_out, 0, sizeof(float), stream);

    hist_kernel<<<BATCHES * BPB, THREADS, 0, stream>>>(pred, targ, gcnt, gsum);
    select_kernel<<<BATCHES, 256, 0, stream>>>(gcnt, gsum, out);
}

// Round 5
// 132.176 us; speedup vs baseline: 1.3041x; 1.3041x over previous
//
#include <hip/hip_runtime.h>

// MAETrimLoss: per-batch sum of k smallest |pred-target|, /(2m), mean over batches.
// One-pass bit-pattern histogram (2048 bins, packed u64 count+fixed-point-sum)
// + parallel-scan selection with within-bin trapezoid interpolation.

#define NBINS     2048        // top 11 bits of |x| bit pattern (sign bit is 0)
#define SHIFT     20          // bits >> 20 < 2^11 since bit31==0
#define BATCHES   32
#define M_ELEMS   307200      // 1*480*640
#define K_RANK    245760      // int(0.8 * M_ELEMS)
#define BPB       64          // blocks per batch -> 2048 blocks total
#define THREADS   256
#define CNT_SHIFT 42
#define SUM_MASK  ((1ull << CNT_SHIFT) - 1ull)
#define FSCALE    1048576.0f      // 2^20 fixed-point scale for the value sum
#define INV_FSCALE (1.0f / 1048576.0f)

typedef unsigned long long u64;

__global__ __launch_bounds__(THREADS) void hist_kernel(
    const float* __restrict__ pred, const float* __restrict__ targ,
    u64* __restrict__ ghist)
{
    __shared__ u64 lh[NBINS];   // 16 KB -> up to 10 blocks/CU by LDS
    for (int i = threadIdx.x; i < NBINS; i += THREADS) lh[i] = 0ull;
    __syncthreads();

    const int b   = blockIdx.x / BPB;
    const int seg = blockIdx.x % BPB;
    const int q4_per_batch = M_ELEMS / 4;          // 76800
    const int q4_per_seg   = q4_per_batch / BPB;   // 1200
    const float4* p4 = reinterpret_cast<const float4*>(pred) + (size_t)b * q4_per_batch;
    const float4* t4 = reinterpret_cast<const float4*>(targ) + (size_t)b * q4_per_batch;

    const int i_end = (seg + 1) * q4_per_seg;
    for (int i = seg * q4_per_seg + threadIdx.x; i < i_end; i += THREADS) {
        float4 pv = p4[i];
        float4 tv = t4[i];
        float a; unsigned bin; u64 v;
        a = fabsf(pv.x - tv.x); bin = __float_as_uint(a) >> SHIFT;
        v = (1ull << CNT_SHIFT) + (u64)(unsigned)fmaf(a, FSCALE, 0.5f);
        atomicAdd(&lh[bin], v);
        a = fabsf(pv.y - tv.y); bin = __float_as_uint(a) >> SHIFT;
        v = (1ull << CNT_SHIFT) + (u64)(unsigned)fmaf(a, FSCALE, 0.5f);
        atomicAdd(&lh[bin], v);
        a = fabsf(pv.z - tv.z); bin = __float_as_uint(a) >> SHIFT;
        v = (1ull << CNT_SHIFT) + (u64)(unsigned)fmaf(a, FSCALE, 0.5f);
        atomicAdd(&lh[bin], v);
        a = fabsf(pv.w - tv.w); bin = __float_as_uint(a) >> SHIFT;
        v = (1ull << CNT_SHIFT) + (u64)(unsigned)fmaf(a, FSCALE, 0.5f);
        atomicAdd(&lh[bin], v);
    }
    __syncthreads();

    u64* gb = ghist + (size_t)b * NBINS;
    for (int i = threadIdx.x; i < NBINS; i += THREADS) {
        u64 v = lh[i];
        if (v) atomicAdd(&gb[i], v);
    }
}

__global__ __launch_bounds__(256) void select_kernel(
    const u64* __restrict__ ghist, float* __restrict__ out)
{
    const int b = blockIdx.x;
    const u64* h = ghist + (size_t)b * NBINS;
    const int per = NBINS / 256;  // 8
    const int t = threadIdx.x;

    // Each thread owns 8 consecutive bins, kept in registers (static indexing).
    u64 vloc[8];
    unsigned c_t = 0; u64 sfix = 0;
    #pragma unroll
    for (int i = 0; i < per; ++i) {
        u64 v = h[t * per + i];
        vloc[i] = v;
        c_t += (unsigned)(v >> CNT_SHIFT);
        sfix += (v & SUM_MASK);
    }
    float s_t = (float)sfix * INV_FSCALE;

    // Hillis-Steele inclusive scan over the 256 chunk totals (counts + sums).
    __shared__ unsigned pc[256];
    __shared__ float    ps[256];
    pc[t] = c_t; ps[t] = s_t;
    __syncthreads();
    for (int off = 1; off < 256; off <<= 1) {
        unsigned a = pc[t]; float sv = ps[t];
        if (t >= off) { a += pc[t - off]; sv += ps[t - off]; }
        __syncthreads();
        pc[t] = a; ps[t] = sv;
        __syncthreads();
    }

    unsigned incl = pc[t];
    unsigned excl = incl - c_t;
    if (excl < (unsigned)K_RANK && incl >= (unsigned)K_RANK) {
        // exactly one thread: the crossing chunk
        unsigned cum = excl;
        float S = ps[t] - s_t;        // full-chunk sums strictly below this chunk
        #pragma unroll
        for (int i = 0; i < per; ++i) {
            u64 v = vloc[i];
            unsigned cb = (unsigned)(v >> CNT_SHIFT);
            if (cum + cb >= (unsigned)K_RANK) {
                unsigned r = (unsigned)K_RANK - cum;   // 1..cb
                unsigned bin = (unsigned)(t * per + i);
                float lo = __uint_as_float(bin << SHIFT);
                float hi = __uint_as_float((bin + 1u) << SHIFT);
                float T  = lo + (hi - lo) * ((float)r / (float)cb);
                S += 0.5f * (lo + T) * (float)r;       // trapezoid partial sum
                break;
            }
            cum += cb;
            S += (float)(v & SUM_MASK) * INV_FSCALE;
        }
        atomicAdd(out, S * (1.0f / (2.0f * (float)M_ELEMS * (float)BATCHES)));
    }
}

extern "C" void kernel_launch(void* const* d_in, const int* in_sizes, int n_in,
                              void* d_out, int out_size, void* d_ws, size_t ws_size,
                              hipStream_t stream)
{
    const float* pred = (const float*)d_in[0];
    const float* targ = (const float*)d_in[1];
    // d_in[2] (mask) is unused by the reference.
    float* out = (float*)d_out;

    u64* ghist = (u64*)d_ws;   // 32 * 2048 * 8 = 512 KB

    hipMemsetAsync(d_ws, 0, (size_t)BATCHES * NBINS * sizeof(u64), stream);
    hipMemsetAsync(d_out, 0, sizeof(float), stream);

    hist_kernel<<<BATCHES * BPB, THREADS, 0, stream>>>(pred, targ, ghist);
    select_kernel<<<BATCHES, 256, 0, stream>>>(ghist, out);
}

// Round 8
// 131.251 us; speedup vs baseline: 1.3133x; 1.0070x over previous
//
#include <hip/hip_runtime.h>

// MAETrimLoss: per-batch sum of k smallest |pred-target|, /(2m), mean over batches.
// One-pass bit-pattern histogram (2048 bins, packed u64 count+fixed-point-sum)
// + parallel-scan selection with within-bin trapezoid interpolation.
//
// R5 change: BPB 64->16, THREADS 256->1024. Load phase keeps full occupancy
// (512 blocks = 2/CU x 16 waves = 32 waves/CU) while the global flush drops
// from ~2048 blocks x ~1k atomics to ~512 x ~1.5k, with per-block staggered
// bin order to avoid same-address atomic bursts.

#define NBINS     2048        // top 11 bits of |x| bit pattern (sign bit is 0)
#define SHIFT     20          // bits >> 20 < 2^11 since bit31==0
#define BATCHES   32
#define M_ELEMS   307200      // 1*480*640
#define K_RANK    245760      // int(0.8 * M_ELEMS)
#define BPB       16          // blocks per batch -> 512 blocks total
#define THREADS   1024        // 16 waves/block
#define CNT_SHIFT 42
#define SUM_MASK  ((1ull << CNT_SHIFT) - 1ull)
#define FSCALE    1048576.0f      // 2^20 fixed-point scale for the value sum
#define INV_FSCALE (1.0f / 1048576.0f)

typedef unsigned long long u64;

__global__ __launch_bounds__(THREADS, 8) void hist_kernel(
    const float* __restrict__ pred, const float* __restrict__ targ,
    u64* __restrict__ ghist)
{
    __shared__ u64 lh[NBINS];   // 16 KB -> 2 blocks/CU easily
    for (int i = threadIdx.x; i < NBINS; i += THREADS) lh[i] = 0ull;
    __syncthreads();

    const int b   = blockIdx.x / BPB;
    const int seg = blockIdx.x % BPB;
    const int q4_per_batch = M_ELEMS / 4;          // 76800
    const int q4_per_seg   = q4_per_batch / BPB;   // 4800
    const float4* p4 = reinterpret_cast<const float4*>(pred) + (size_t)b * q4_per_batch;
    const float4* t4 = reinterpret_cast<const float4*>(targ) + (size_t)b * q4_per_batch;

    const int i_end = (seg + 1) * q4_per_seg;
    for (int i = seg * q4_per_seg + threadIdx.x; i < i_end; i += THREADS) {
        float4 pv = p4[i];
        float4 tv = t4[i];
        float a; unsigned bin; u64 v;
        a = fabsf(pv.x - tv.x); bin = __float_as_uint(a) >> SHIFT;
        v = (1ull << CNT_SHIFT) + (u64)(unsigned)fmaf(a, FSCALE, 0.5f);
        atomicAdd(&lh[bin], v);
        a = fabsf(pv.y - tv.y); bin = __float_as_uint(a) >> SHIFT;
        v = (1ull << CNT_SHIFT) + (u64)(unsigned)fmaf(a, FSCALE, 0.5f);
        atomicAdd(&lh[bin], v);
        a = fabsf(pv.z - tv.z); bin = __float_as_uint(a) >> SHIFT;
        v = (1ull << CNT_SHIFT) + (u64)(unsigned)fmaf(a, FSCALE, 0.5f);
        atomicAdd(&lh[bin], v);
        a = fabsf(pv.w - tv.w); bin = __float_as_uint(a) >> SHIFT;
        v = (1ull << CNT_SHIFT) + (u64)(unsigned)fmaf(a, FSCALE, 0.5f);
        atomicAdd(&lh[bin], v);
    }
    __syncthreads();

    // Flush with per-block staggered bin order: concurrent blocks start at
    // different bins so the global atomics don't burst on the same lines.
    u64* gb = ghist + (size_t)b * NBINS;
    for (int k = threadIdx.x; k < NBINS; k += THREADS) {
        int i = (k + seg * 128) & (NBINS - 1);
        u64 v = lh[i];
        if (v) atomicAdd(&gb[i], v);
    }
}

__global__ __launch_bounds__(256) void select_kernel(
    const u64* __restrict__ ghist, float* __restrict__ out)
{
    const int b = blockIdx.x;
    const u64* h = ghist + (size_t)b * NBINS;
    const int per = NBINS / 256;  // 8
    const int t = threadIdx.x;

    // Each thread owns 8 consecutive bins, kept in registers (static indexing).
    u64 vloc[8];
    unsigned c_t = 0; u64 sfix = 0;
    #pragma unroll
    for (int i = 0; i < per; ++i) {
        u64 v = h[t * per + i];
        vloc[i] = v;
        c_t += (unsigned)(v >> CNT_SHIFT);
        sfix += (v & SUM_MASK);
    }
    float s_t = (float)sfix * INV_FSCALE;

    // Hillis-Steele inclusive scan over the 256 chunk totals (counts + sums).
    __shared__ unsigned pc[256];
    __shared__ float    ps[256];
    pc[t] = c_t; ps[t] = s_t;
    __syncthreads();
    for (int off = 1; off < 256; off <<= 1) {
        unsigned a = pc[t]; float sv = ps[t];
        if (t >= off) { a += pc[t - off]; sv += ps[t - off]; }
        __syncthreads();
        pc[t] = a; ps[t] = sv;
        __syncthreads();
    }

    unsigned incl = pc[t];
    unsigned excl = incl - c_t;
    if (excl < (unsigned)K_RANK && incl >= (unsigned)K_RANK) {
        // exactly one thread: the crossing chunk
        unsigned cum = excl;
        float S = ps[t] - s_t;        // full-chunk sums strictly below this chunk
        #pragma unroll
        for (int i = 0; i < per; ++i) {
            u64 v = vloc[i];
            unsigned cb = (unsigned)(v >> CNT_SHIFT);
            if (cum + cb >= (unsigned)K_RANK) {
                unsigned r = (unsigned)K_RANK - cum;   // 1..cb
                unsigned bin = (unsigned)(t * per + i);
                float lo = __uint_as_float(bin << SHIFT);
                float hi = __uint_as_float((bin + 1u) << SHIFT);
                float T  = lo + (hi - lo) * ((float)r / (float)cb);
                S += 0.5f * (lo + T) * (float)r;       // trapezoid partial sum
                break;
            }
            cum += cb;
            S += (float)(v & SUM_MASK) * INV_FSCALE;
        }
        atomicAdd(out, S * (1.0f / (2.0f * (float)M_ELEMS * (float)BATCHES)));
    }
}

extern "C" void kernel_launch(void* const* d_in, const int* in_sizes, int n_in,
                              void* d_out, int out_size, void* d_ws, size_t ws_size,
                              hipStream_t stream)
{
    const float* pred = (const float*)d_in[0];
    const float* targ = (const float*)d_in[1];
    // d_in[2] (mask) is unused by the reference.
    float* out = (float*)d_out;

    u64* ghist = (u64*)d_ws;   // 32 * 2048 * 8 = 512 KB

    hipMemsetAsync(d_ws, 0, (size_t)BATCHES * NBINS * sizeof(u64), stream);
    hipMemsetAsync(d_out, 0, sizeof(float), stream);

    hist_kernel<<<BATCHES * BPB, THREADS, 0, stream>>>(pred, targ, ghist);
    select_kernel<<<BATCHES, 256, 0, stream>>>(ghist, out);
}